// Round 1
// baseline (194.415 us; speedup 1.0000x reference)
//
#include <hip/hip_runtime.h>
#include <hip/hip_bf16.h>
#include <math.h>

// Problem constants
#define BB 2
#define TT 2048
#define CC 256
#define HH 4
#define DD 64
#define WW 64
#define TQ 2047          // T - S
#define N_KQV 768        // 3*H*D

// ---------------------------------------------------------------------------
// Tiled f32 GEMM: C[M,N] = A[M,K] * B[N,K]^T (+ bias), optional "row%2048==0 is
// zero" predicate on A (used for the S=1 shift in the output projection).
// LDS stored transposed (As[k][m]) so the inner loop reads contiguous float4.
// ---------------------------------------------------------------------------
template<int BMv, int BNv, int TMv, int TNv, bool ZROW, bool BIAS>
__global__ __launch_bounds__(256)
void gemm_bt_f32(const float* __restrict__ A, const float* __restrict__ Bm,
                 const float* __restrict__ bias, float* __restrict__ C,
                 int M, int N, int K) {
    constexpr int BK = 16;
    constexpr int PAD = 4;
    __shared__ float As[BK][BMv + PAD];
    __shared__ float Bs[BK][BNv + PAD];

    const int tid = threadIdx.x;
    const int m0 = blockIdx.x * BMv;
    const int n0 = blockIdx.y * BNv;
    const int tm = (tid >> 4) * TMv;
    const int tn = (tid & 15) * TNv;

    float acc[TMv][TNv];
#pragma unroll
    for (int i = 0; i < TMv; ++i)
#pragma unroll
        for (int j = 0; j < TNv; ++j) acc[i][j] = 0.f;

    for (int k0 = 0; k0 < K; k0 += BK) {
        // ---- stage A tile (BMv x BK) transposed into As[k][m]
#pragma unroll
        for (int l = 0; l < BMv / 64; ++l) {
            int fi = tid + l * 256;      // float4 index within tile
            int r  = fi >> 2;            // tile row
            int kc = (fi & 3) * 4;       // k column (x4)
            int gr = m0 + r;
            float4 v;
            if (!ZROW || (gr & (TT - 1)) != 0)
                v = *reinterpret_cast<const float4*>(A + (size_t)gr * K + k0 + kc);
            else
                v = make_float4(0.f, 0.f, 0.f, 0.f);
            As[kc + 0][r] = v.x; As[kc + 1][r] = v.y;
            As[kc + 2][r] = v.z; As[kc + 3][r] = v.w;
        }
        // ---- stage B tile (BNv x BK) transposed into Bs[k][n]
#pragma unroll
        for (int l = 0; l < BNv / 64; ++l) {
            int fi = tid + l * 256;
            int r  = fi >> 2;
            int kc = (fi & 3) * 4;
            float4 v = *reinterpret_cast<const float4*>(Bm + (size_t)(n0 + r) * K + k0 + kc);
            Bs[kc + 0][r] = v.x; Bs[kc + 1][r] = v.y;
            Bs[kc + 2][r] = v.z; Bs[kc + 3][r] = v.w;
        }
        __syncthreads();

#pragma unroll
        for (int kk = 0; kk < BK; ++kk) {
            float a[TMv], b[TNv];
#pragma unroll
            for (int i = 0; i < TMv; i += 4)
                *reinterpret_cast<float4*>(&a[i]) =
                    *reinterpret_cast<const float4*>(&As[kk][tm + i]);
#pragma unroll
            for (int j = 0; j < TNv; j += 4)
                *reinterpret_cast<float4*>(&b[j]) =
                    *reinterpret_cast<const float4*>(&Bs[kk][tn + j]);
#pragma unroll
            for (int i = 0; i < TMv; ++i)
#pragma unroll
                for (int j = 0; j < TNv; ++j)
                    acc[i][j] = fmaf(a[i], b[j], acc[i][j]);
        }
        __syncthreads();
    }

    // ---- epilogue
#pragma unroll
    for (int i = 0; i < TMv; ++i) {
#pragma unroll
        for (int j = 0; j < TNv; j += 4) {
            float4 v;
            v.x = acc[i][j + 0]; v.y = acc[i][j + 1];
            v.z = acc[i][j + 2]; v.w = acc[i][j + 3];
            if (BIAS) {
                v.x += bias[n0 + tn + j + 0];
                v.y += bias[n0 + tn + j + 1];
                v.z += bias[n0 + tn + j + 2];
                v.w += bias[n0 + tn + j + 3];
            }
            *reinterpret_cast<float4*>(C + (size_t)(m0 + tm + i) * N + n0 + tn + j) = v;
        }
    }
}

// ---------------------------------------------------------------------------
// Window attention: one wave per (b, h, t).
// Phase 1: lane = w. score = q[j]·(k[j]+q_pos[w]) / 8, j = t-63+w (masked j<0).
// Wave softmax via shfl_xor. Write wei.
// Phase 2: lane = d. out[d] = sum_w wei[w]*(v[j,d]+v_pos[w,d]); write shifted
// into attnS[b, t+1, h*64+d].
// ---------------------------------------------------------------------------
__global__ __launch_bounds__(256)
void attn_win(const float* __restrict__ kqv, const float* __restrict__ q_pos,
              const float* __restrict__ v_pos, float* __restrict__ wei_out,
              float* __restrict__ attnS) {
    const int wid  = blockIdx.x * 4 + (threadIdx.x >> 6);
    const int lane = threadIdx.x & 63;
    const int TOT = BB * HH * TQ;
    if (wid >= TOT) return;
    const int t  = wid % TQ;
    const int bh = wid / TQ;
    const int h  = bh % HH;
    const int b  = bh / HH;

    const int w = lane;
    const int j = t - 63 + w;

    float s = -INFINITY;
    if (j >= 0) {
        const float* krow = kqv + ((size_t)(b * TT + j)) * N_KQV + h * DD;
        const float* qrow = krow + 256;
        const float* qp   = q_pos + (size_t)(w * HH + h) * DD;
        float acc = 0.f;
#pragma unroll
        for (int d = 0; d < DD; d += 4) {
            float4 qv = *reinterpret_cast<const float4*>(qrow + d);
            float4 kv = *reinterpret_cast<const float4*>(krow + d);
            float4 pv = *reinterpret_cast<const float4*>(qp + d);
            acc = fmaf(qv.x, kv.x + pv.x, acc);
            acc = fmaf(qv.y, kv.y + pv.y, acc);
            acc = fmaf(qv.z, kv.z + pv.z, acc);
            acc = fmaf(qv.w, kv.w + pv.w, acc);
        }
        s = acc * 0.125f;
    }

    // wave softmax over 64 lanes
    float m = s;
#pragma unroll
    for (int off = 32; off; off >>= 1) m = fmaxf(m, __shfl_xor(m, off));
    float p = (j >= 0) ? __expf(s - m) : 0.f;
    float sum = p;
#pragma unroll
    for (int off = 32; off; off >>= 1) sum += __shfl_xor(sum, off);
    float wei = p / sum;

    wei_out[(((size_t)b * TQ + t) * WW + w) * HH + h] = wei;

    // phase 2: lane = d
    const int d = lane;
    const float* vbase = kqv + (size_t)(b * TT) * N_KQV + 512 + h * DD + d;
    const float* vp    = v_pos + h * DD + d;
    float o = 0.f;
    const int w0 = (t >= 63) ? 0 : (63 - t);
    for (int ww = w0; ww < WW; ++ww) {
        float wv = __shfl(wei, ww);
        int jj = t - 63 + ww;
        o = fmaf(wv, vbase[(size_t)jj * N_KQV] + vp[ww * (HH * DD)], o);
    }
    attnS[((size_t)(b * TT) + (t + 1)) * (HH * DD) + h * DD + d] = o;
}

// ---------------------------------------------------------------------------
extern "C" void kernel_launch(void* const* d_in, const int* in_sizes, int n_in,
                              void* d_out, int out_size, void* d_ws, size_t ws_size,
                              hipStream_t stream) {
    const float* x     = (const float*)d_in[0];   // (B,T,C)
    const float* w_kqv = (const float*)d_in[1];   // (768,256)
    const float* w_out = (const float*)d_in[2];   // (256,256)
    const float* b_out = (const float*)d_in[3];   // (256,)
    const float* q_pos = (const float*)d_in[4];   // (W,H,D)
    const float* v_pos = (const float*)d_in[5];   // (W,H,D)

    float* y   = (float*)d_out;                              // (B,T,256)
    float* wei = (float*)d_out + (size_t)BB * TT * CC;       // (B,Tq,W,H)

    float* kqv   = (float*)d_ws;                             // (B*T, 768)
    float* attnS = (float*)d_ws + (size_t)BB * TT * N_KQV;   // (B*T, 256), row t=0/b unused

    // K1: kqv = x @ w_kqv^T   (M=4096, N=768, K=256)
    gemm_bt_f32<128, 128, 8, 8, false, false>
        <<<dim3((BB * TT) / 128, N_KQV / 128), 256, 0, stream>>>(
            x, w_kqv, nullptr, kqv, BB * TT, N_KQV, CC);

    // K2: window attention -> wei (d_out) + attnS (shifted by 1)
    {
        const int tot_waves = BB * HH * TQ;
        const int blocks = (tot_waves + 3) / 4;
        attn_win<<<blocks, 256, 0, stream>>>(kqv, q_pos, v_pos, wei, attnS);
    }

    // K3: y = attnS @ w_out^T + b_out  (rows with t==0 treated as zero)
    gemm_bt_f32<64, 64, 4, 4, true, true>
        <<<dim3((BB * TT) / 64, CC / 64), 256, 0, stream>>>(
            attnS, w_out, b_out, y, BB * TT, CC, CC);
}

// Round 2
// 75.394 us; speedup vs baseline: 2.5787x; 2.5787x over previous
//
#include <hip/hip_runtime.h>
#include <hip/hip_bf16.h>
#include <math.h>

#define BB 2
#define TT 2048
#define CC 256
#define HH 4
#define DD 64
#define WW 64
#define TQ 2047
#define N_KQV 768

typedef __attribute__((ext_vector_type(8))) short bf16x8;
typedef __attribute__((ext_vector_type(4))) float f32x4;

__device__ inline short f2bf(float x) {
    unsigned u = __float_as_uint(x);
    u += 0x7FFF + ((u >> 16) & 1);
    return (short)(u >> 16);
}

// ---------------------------------------------------------------------------
// f32 GEMM: C[M,N] = A[M,K] * B[N,K]^T (+bias); ZROW: rows with (r%2048)==0 are 0.
// ---------------------------------------------------------------------------
template<int BMv, int BNv, int TMv, int TNv, bool ZROW, bool BIAS>
__global__ __launch_bounds__(256)
void gemm_bt_f32(const float* __restrict__ A, const float* __restrict__ Bm,
                 const float* __restrict__ bias, float* __restrict__ C,
                 int M, int N, int K) {
    constexpr int BK = 16;
    constexpr int PAD = 4;
    __shared__ float As[BK][BMv + PAD];
    __shared__ float Bs[BK][BNv + PAD];

    const int tid = threadIdx.x;
    const int m0 = blockIdx.x * BMv;
    const int n0 = blockIdx.y * BNv;
    const int tm = (tid >> 4) * TMv;
    const int tn = (tid & 15) * TNv;

    float acc[TMv][TNv];
#pragma unroll
    for (int i = 0; i < TMv; ++i)
#pragma unroll
        for (int j = 0; j < TNv; ++j) acc[i][j] = 0.f;

    for (int k0 = 0; k0 < K; k0 += BK) {
#pragma unroll
        for (int l = 0; l < BMv / 64; ++l) {
            int fi = tid + l * 256;
            int r  = fi >> 2;
            int kc = (fi & 3) * 4;
            int gr = m0 + r;
            float4 v;
            if (!ZROW || (gr & (TT - 1)) != 0)
                v = *reinterpret_cast<const float4*>(A + (size_t)gr * K + k0 + kc);
            else
                v = make_float4(0.f, 0.f, 0.f, 0.f);
            As[kc + 0][r] = v.x; As[kc + 1][r] = v.y;
            As[kc + 2][r] = v.z; As[kc + 3][r] = v.w;
        }
#pragma unroll
        for (int l = 0; l < BNv / 64; ++l) {
            int fi = tid + l * 256;
            int r  = fi >> 2;
            int kc = (fi & 3) * 4;
            float4 v = *reinterpret_cast<const float4*>(Bm + (size_t)(n0 + r) * K + k0 + kc);
            Bs[kc + 0][r] = v.x; Bs[kc + 1][r] = v.y;
            Bs[kc + 2][r] = v.z; Bs[kc + 3][r] = v.w;
        }
        __syncthreads();

#pragma unroll
        for (int kk = 0; kk < BK; ++kk) {
            float a[TMv], b[TNv];
#pragma unroll
            for (int i = 0; i < TMv; i += 4)
                *reinterpret_cast<float4*>(&a[i]) =
                    *reinterpret_cast<const float4*>(&As[kk][tm + i]);
#pragma unroll
            for (int j = 0; j < TNv; j += 4)
                *reinterpret_cast<float4*>(&b[j]) =
                    *reinterpret_cast<const float4*>(&Bs[kk][tn + j]);
#pragma unroll
            for (int i = 0; i < TMv; ++i)
#pragma unroll
                for (int j = 0; j < TNv; ++j)
                    acc[i][j] = fmaf(a[i], b[j], acc[i][j]);
        }
        __syncthreads();
    }

#pragma unroll
    for (int i = 0; i < TMv; ++i) {
#pragma unroll
        for (int j = 0; j < TNv; j += 4) {
            float4 v;
            v.x = acc[i][j + 0]; v.y = acc[i][j + 1];
            v.z = acc[i][j + 2]; v.w = acc[i][j + 3];
            if (BIAS) {
                v.x += bias[n0 + tn + j + 0];
                v.y += bias[n0 + tn + j + 1];
                v.z += bias[n0 + tn + j + 2];
                v.w += bias[n0 + tn + j + 3];
            }
            *reinterpret_cast<float4*>(C + (size_t)(m0 + tm + i) * N + n0 + tn + j) = v;
        }
    }
}

// ---------------------------------------------------------------------------
// K2: scores[b,h,t,w] = 0.125 * ( k[j]·q[j] + q_pos[w]·q[j] ),  j = t-63+w,
// written pre-shifted (t = j+63-w).  One block per (b,h,64-row j-tile).
// ---------------------------------------------------------------------------
__global__ __launch_bounds__(256)
void score_gemm(const float* __restrict__ kqv, const float* __restrict__ q_pos,
                float* __restrict__ scores) {
    __shared__ float qaT[64][68];   // [d][j_local]
    __shared__ float qbT[64][68];   // [d][w]
    __shared__ float pt[64][17];    // k·q partials
    __shared__ float dq[64];

    const int tid = threadIdx.x;
    const int bid = blockIdx.x;
    const int jt  = bid & 31;
    const int h   = (bid >> 5) & 3;
    const int b   = bid >> 7;
    const int j0  = jt * 64;

    // stage q rows (transposed) + k·q partials
#pragma unroll
    for (int it = 0; it < 4; ++it) {
        int fi = tid + it * 256;        // 0..1023
        int r  = fi >> 4;
        int c4 = (fi & 15) * 4;
        const float* base = kqv + ((size_t)(b * TT + j0 + r)) * N_KQV + h * DD;
        float4 kv = *reinterpret_cast<const float4*>(base + c4);
        float4 qv = *reinterpret_cast<const float4*>(base + 256 + c4);
        qaT[c4 + 0][r] = qv.x; qaT[c4 + 1][r] = qv.y;
        qaT[c4 + 2][r] = qv.z; qaT[c4 + 3][r] = qv.w;
        pt[r][fi & 15] = qv.x * kv.x + qv.y * kv.y + qv.z * kv.z + qv.w * kv.w;
    }
    // stage q_pos (transposed)
#pragma unroll
    for (int it = 0; it < 4; ++it) {
        int fi = tid + it * 256;
        int w  = fi >> 4;
        int c4 = (fi & 15) * 4;
        float4 v = *reinterpret_cast<const float4*>(q_pos + (size_t)(w * HH + h) * DD + c4);
        qbT[c4 + 0][w] = v.x; qbT[c4 + 1][w] = v.y;
        qbT[c4 + 2][w] = v.z; qbT[c4 + 3][w] = v.w;
    }
    __syncthreads();
    if (tid < 64) {
        float s = 0.f;
#pragma unroll
        for (int c = 0; c < 16; ++c) s += pt[tid][c];
        dq[tid] = s;
    }
    __syncthreads();

    const int tww = tid & 15;
    const int tjj = tid >> 4;
    float acc[4][4];
#pragma unroll
    for (int i = 0; i < 4; ++i)
#pragma unroll
        for (int j = 0; j < 4; ++j) acc[i][j] = 0.f;

#pragma unroll 2
    for (int d = 0; d < 64; ++d) {
        float4 a  = *reinterpret_cast<const float4*>(&qaT[d][tjj * 4]);
        float4 b4 = *reinterpret_cast<const float4*>(&qbT[d][tww * 4]);
        const float* ap = &a.x; const float* bp = &b4.x;
#pragma unroll
        for (int i = 0; i < 4; ++i)
#pragma unroll
            for (int j = 0; j < 4; ++j)
                acc[i][j] = fmaf(ap[i], bp[j], acc[i][j]);
    }

#pragma unroll
    for (int i = 0; i < 4; ++i) {
        int jl = tjj * 4 + i;
        int j  = j0 + jl;
        float dqv = dq[jl];
#pragma unroll
        for (int jj = 0; jj < 4; ++jj) {
            int w = tww * 4 + jj;
            int t = j + 63 - w;
            if (t < TQ)
                scores[(((size_t)(b * HH + h) * TQ + t) << 6) + w] =
                    (acc[i][jj] + dqv) * 0.125f;
        }
    }
}

// ---------------------------------------------------------------------------
// K3: fused softmax + PV (MFMA).  One block per (b,h,64-t tile), 4 waves,
// wave handles 16 t-rows.  out[16,64] = P'banded[16,96] @ V[96,64]
//                                      + Pdense[16,64] @ v_pos[64,64].
// ---------------------------------------------------------------------------
#define OFF_VT 0                        // bf16 [64][168]  vT[d][j']   j' = j-(t0-63)
#define OFF_VP 10752                    // bf16 [64][72]   vpT[d][w]
#define OFF_PP 15360                    // per-wave bf16 [16][104] banded
#define OFF_PD (15360 + 4*1664)         // per-wave bf16 [16][72]  dense
#define LDS_U16 (15360 + 4*1664 + 4*1152)

__global__ __launch_bounds__(256)
void attn_fused(const float* __restrict__ kqv, const float* __restrict__ scores,
                const float* __restrict__ v_pos, float* __restrict__ wei_out,
                float* __restrict__ attnS) {
    __shared__ short lds[LDS_U16];

    const int tid  = threadIdx.x;
    const int wv   = tid >> 6;
    const int lane = tid & 63;
    const int bid  = blockIdx.x;
    const int tile = bid & 31;
    const int h    = (bid >> 5) & 3;
    const int b    = bid >> 7;
    const int t0   = tile * 64;

    // ---- stage vT: rows j' = 0..159  (j = t0-63+j')
#pragma unroll
    for (int it = 0; it < 10; ++it) {
        int fi = tid + it * 256;        // 0..2559
        int r  = fi >> 4;
        int c4 = (fi & 15) * 4;
        int j  = t0 - 63 + r;
        float4 v = make_float4(0.f, 0.f, 0.f, 0.f);
        if (j >= 0 && j < TT)
            v = *reinterpret_cast<const float4*>(
                    kqv + ((size_t)(b * TT + j)) * N_KQV + 512 + h * DD + c4);
        lds[OFF_VT + (c4 + 0) * 168 + r] = f2bf(v.x);
        lds[OFF_VT + (c4 + 1) * 168 + r] = f2bf(v.y);
        lds[OFF_VT + (c4 + 2) * 168 + r] = f2bf(v.z);
        lds[OFF_VT + (c4 + 3) * 168 + r] = f2bf(v.w);
    }
    // ---- stage vpT
#pragma unroll
    for (int it = 0; it < 4; ++it) {
        int fi = tid + it * 256;
        int w  = fi >> 4;
        int c4 = (fi & 15) * 4;
        float4 v = *reinterpret_cast<const float4*>(v_pos + (size_t)(w * HH + h) * DD + c4);
        lds[OFF_VP + (c4 + 0) * 72 + w] = f2bf(v.x);
        lds[OFF_VP + (c4 + 1) * 72 + w] = f2bf(v.y);
        lds[OFF_VP + (c4 + 2) * 72 + w] = f2bf(v.z);
        lds[OFF_VP + (c4 + 3) * 72 + w] = f2bf(v.w);
    }
    // ---- zero banded P' (4 waves x 16 x 104 u16 = 3328 u32)
    {
        unsigned int* pz = reinterpret_cast<unsigned int*>(lds + OFF_PP);
#pragma unroll
        for (int i = 0; i < 13; ++i) pz[tid + i * 256] = 0u;
    }
    __syncthreads();

    // ---- score + softmax; wave wv owns t = ta..ta+15
    const int ta = t0 + wv * 16;
    const int w  = lane;
#pragma unroll
    for (int i = 0; i < 16; ++i) {
        int t = ta + i;
        float wei = 0.f;
        if (t < TQ) {
            int j = t - 63 + w;
            float s = (j >= 0)
                ? scores[(((size_t)(b * HH + h) * TQ + t) << 6) + w]
                : -INFINITY;
            float m = s;
#pragma unroll
            for (int off = 32; off; off >>= 1) m = fmaxf(m, __shfl_xor(m, off));
            float p = (j >= 0) ? __expf(s - m) : 0.f;
            float sum = p;
#pragma unroll
            for (int off = 32; off; off >>= 1) sum += __shfl_xor(sum, off);
            wei = p / sum;
            wei_out[(((size_t)b * TQ + t) * WW + w) * HH + h] = wei;
        }
        short wb = f2bf(wei);
        lds[OFF_PD + wv * 1152 + i * 72 + w]        = wb;
        lds[OFF_PP + wv * 1664 + i * 104 + (i + w)] = wb;
    }

    // ---- MFMA PV
    const int col = lane & 15;
    const int kg  = lane >> 4;
    f32x4 acc[4];
#pragma unroll
    for (int dt = 0; dt < 4; ++dt) acc[dt] = (f32x4){0.f, 0.f, 0.f, 0.f};

    const int jbase = wv * 16;
#pragma unroll
    for (int ks = 0; ks < 3; ++ks) {
        bf16x8 afrag = *reinterpret_cast<const bf16x8*>(
            &lds[OFF_PP + wv * 1664 + col * 104 + ks * 32 + kg * 8]);
#pragma unroll
        for (int dt = 0; dt < 4; ++dt) {
            bf16x8 bfrag = *reinterpret_cast<const bf16x8*>(
                &lds[OFF_VT + (dt * 16 + col) * 168 + jbase + ks * 32 + kg * 8]);
            acc[dt] = __builtin_amdgcn_mfma_f32_16x16x32_bf16(afrag, bfrag, acc[dt], 0, 0, 0);
        }
    }
#pragma unroll
    for (int ks = 0; ks < 2; ++ks) {
        bf16x8 afrag = *reinterpret_cast<const bf16x8*>(
            &lds[OFF_PD + wv * 1152 + col * 72 + ks * 32 + kg * 8]);
#pragma unroll
        for (int dt = 0; dt < 4; ++dt) {
            bf16x8 bfrag = *reinterpret_cast<const bf16x8*>(
                &lds[OFF_VP + (dt * 16 + col) * 72 + ks * 32 + kg * 8]);
            acc[dt] = __builtin_amdgcn_mfma_f32_16x16x32_bf16(afrag, bfrag, acc[dt], 0, 0, 0);
        }
    }

    // ---- write attnS shifted by +1 row
#pragma unroll
    for (int dt = 0; dt < 4; ++dt) {
#pragma unroll
        for (int r = 0; r < 4; ++r) {
            int t = ta + kg * 4 + r;
            if (t < TQ)
                attnS[((size_t)(b * TT) + t + 1) * CC + h * DD + dt * 16 + col] = acc[dt][r];
        }
    }
}

// ---------------------------------------------------------------------------
extern "C" void kernel_launch(void* const* d_in, const int* in_sizes, int n_in,
                              void* d_out, int out_size, void* d_ws, size_t ws_size,
                              hipStream_t stream) {
    const float* x     = (const float*)d_in[0];
    const float* w_kqv = (const float*)d_in[1];
    const float* w_out = (const float*)d_in[2];
    const float* b_out = (const float*)d_in[3];
    const float* q_pos = (const float*)d_in[4];
    const float* v_pos = (const float*)d_in[5];

    float* y   = (float*)d_out;
    float* wei = (float*)d_out + (size_t)BB * TT * CC;

    float* kqv    = (float*)d_ws;
    float* attnS  = kqv + (size_t)BB * TT * N_KQV;
    float* scores = attnS + (size_t)BB * TT * CC;

    // K1: kqv = x @ w_kqv^T   (M=4096, N=768, K=256)
    gemm_bt_f32<64, 64, 4, 4, false, false>
        <<<dim3((BB * TT) / 64, N_KQV / 64), 256, 0, stream>>>(
            x, w_kqv, nullptr, kqv, BB * TT, N_KQV, CC);

    // K2: pre-shifted scaled scores
    score_gemm<<<BB * HH * 32, 256, 0, stream>>>(kqv, q_pos, scores);

    // K3: softmax + MFMA PV
    attn_fused<<<BB * HH * 32, 256, 0, stream>>>(kqv, scores, v_pos, wei, attnS);

    // K4: y = attnS @ w_out^T + b_out  (t==0 rows forced zero)
    gemm_bt_f32<64, 64, 4, 4, true, true>
        <<<dim3((BB * TT) / 64, CC / 64), 256, 0, stream>>>(
            attnS, w_out, b_out, y, BB * TT, CC, CC);
}

// Round 3
// 49.083 us; speedup vs baseline: 3.9609x; 1.5360x over previous
//
#include <hip/hip_runtime.h>
#include <hip/hip_bf16.h>
#include <math.h>

#define BB 2
#define TT 2048
#define CC 256
#define HH 4
#define DD 64
#define WW 64
#define TQ 2047
#define N_KQV 768

typedef __attribute__((ext_vector_type(8))) short bf16x8;
typedef __attribute__((ext_vector_type(4))) float f32x4;

__device__ inline short f2bf(float x) {
    unsigned u = __float_as_uint(x);
    u += 0x7FFF + ((u >> 16) & 1);
    return (short)(u >> 16);
}
__device__ inline float bf2f(short s) {
    return __uint_as_float(((unsigned)(unsigned short)s) << 16);
}
__device__ inline bf16x8 cvt8(float4 a, float4 b) {
    bf16x8 r;
    r[0] = f2bf(a.x); r[1] = f2bf(a.y); r[2] = f2bf(a.z); r[3] = f2bf(a.w);
    r[4] = f2bf(b.x); r[5] = f2bf(b.y); r[6] = f2bf(b.z); r[7] = f2bf(b.w);
    return r;
}

// ---------------------------------------------------------------------------
// bf16-MFMA GEMM: C[M,N] = A[M,K] @ B[N,K]^T (+bias).
// A: f32 (converted in staging) or bf16 per ABF.  B: f32 weights.
// C: bf16 or f32 per CBF.  ZROW: rows with (m % 2048)==0 read as zero.
// BK=32, LDS pad to 40 shorts (2-way = free bank aliasing on frag reads).
// ---------------------------------------------------------------------------
template<bool ABF, int BM, int BN, int WR, int WC, bool ZROW, bool BIAS, bool CBF>
__global__ __launch_bounds__(256)
void gemm_mfma(const void* __restrict__ Av, const float* __restrict__ Bm,
               const float* __restrict__ bias, void* __restrict__ Cv,
               int M, int N, int K) {
    constexpr int BK = 32;
    constexpr int LDA = BK + 8;
    constexpr int MR = BM / (WR * 16);
    constexpr int NR = BN / (WC * 16);
    __shared__ short As[BM][LDA];
    __shared__ short Bs[BN][LDA];

    const int tid = threadIdx.x;
    const int m0 = blockIdx.x * BM, n0 = blockIdx.y * BN;
    const int wv = tid >> 6, lane = tid & 63;
    const int wr = wv / WC, wc = wv % WC;
    const int col = lane & 15, kg = lane >> 4;

    f32x4 acc[MR][NR];
#pragma unroll
    for (int i = 0; i < MR; ++i)
#pragma unroll
        for (int j = 0; j < NR; ++j) acc[i][j] = (f32x4){0.f, 0.f, 0.f, 0.f};

    for (int k0 = 0; k0 < K; k0 += BK) {
        // ---- stage A (convert to bf16 if needed)
#pragma unroll
        for (int it = 0; it < (BM * 4) / 256; ++it) {
            int fi = tid + it * 256;
            int r = fi >> 2, c8 = (fi & 3) << 3;
            int gr = m0 + r;
            bf16x8 sv;
            if (ZROW && ((gr & (TT - 1)) == 0)) {
                sv = (bf16x8){0, 0, 0, 0, 0, 0, 0, 0};
            } else if constexpr (ABF) {
                sv = *reinterpret_cast<const bf16x8*>(
                    (const short*)Av + (size_t)gr * K + k0 + c8);
            } else {
                const float* ap = (const float*)Av + (size_t)gr * K + k0 + c8;
                float4 v0 = *reinterpret_cast<const float4*>(ap);
                float4 v1 = *reinterpret_cast<const float4*>(ap + 4);
                sv = cvt8(v0, v1);
            }
            *reinterpret_cast<bf16x8*>(&As[r][c8]) = sv;
        }
        // ---- stage B (f32 -> bf16)
#pragma unroll
        for (int it = 0; it < (BN * 4) / 256; ++it) {
            int fi = tid + it * 256;
            int r = fi >> 2, c8 = (fi & 3) << 3;
            const float* bp = Bm + (size_t)(n0 + r) * K + k0 + c8;
            float4 v0 = *reinterpret_cast<const float4*>(bp);
            float4 v1 = *reinterpret_cast<const float4*>(bp + 4);
            *reinterpret_cast<bf16x8*>(&Bs[r][c8]) = cvt8(v0, v1);
        }
        __syncthreads();

        bf16x8 af[MR], bfr[NR];
#pragma unroll
        for (int i = 0; i < MR; ++i)
            af[i] = *reinterpret_cast<const bf16x8*>(
                &As[wr * MR * 16 + i * 16 + col][kg * 8]);
#pragma unroll
        for (int j = 0; j < NR; ++j)
            bfr[j] = *reinterpret_cast<const bf16x8*>(
                &Bs[wc * NR * 16 + j * 16 + col][kg * 8]);
#pragma unroll
        for (int i = 0; i < MR; ++i)
#pragma unroll
            for (int j = 0; j < NR; ++j)
                acc[i][j] = __builtin_amdgcn_mfma_f32_16x16x32_bf16(
                    af[i], bfr[j], acc[i][j], 0, 0, 0);
        __syncthreads();
    }

#pragma unroll
    for (int i = 0; i < MR; ++i) {
#pragma unroll
        for (int j = 0; j < NR; ++j) {
#pragma unroll
            for (int r = 0; r < 4; ++r) {
                int m = m0 + wr * MR * 16 + i * 16 + kg * 4 + r;
                int n = n0 + wc * NR * 16 + j * 16 + col;
                float v = acc[i][j][r];
                if (BIAS) v += bias[n];
                if constexpr (CBF)
                    ((short*)Cv)[(size_t)m * N + n] = f2bf(v);
                else
                    ((float*)Cv)[(size_t)m * N + n] = v;
            }
        }
    }
}

// ---------------------------------------------------------------------------
// K2: scores[b,h,t,w] = 0.125*(k[j]·q[j] + q[j]·q_pos[w]), j=t-63+w, written
// pre-shifted at t=j+63-w.  qq via MFMA (bf16), dq via VALU dot.
// One block per (b,h,64-row j tile).
// ---------------------------------------------------------------------------
__global__ __launch_bounds__(256)
void score_gemm(const short* __restrict__ kqvb, const float* __restrict__ q_pos,
                float* __restrict__ scores) {
    __shared__ short Qs[64][72];
    __shared__ short Ps[64][72];
    __shared__ float part[64][4];
    __shared__ float dq[64];

    const int tid = threadIdx.x;
    const int bid = blockIdx.x;
    const int jt = bid & 31, h = (bid >> 5) & 3, b = bid >> 7;
    const int j0 = jt * 64;

#pragma unroll
    for (int it = 0; it < 2; ++it) {
        int fi = tid + it * 256;
        int r = fi >> 3, c8 = (fi & 7) << 3;
        *reinterpret_cast<bf16x8*>(&Qs[r][c8]) =
            *reinterpret_cast<const bf16x8*>(
                kqvb + ((size_t)(b * TT + j0 + r)) * N_KQV + 256 + h * DD + c8);
        const float* pp = q_pos + (size_t)(r * HH + h) * DD + c8;
        float4 v0 = *reinterpret_cast<const float4*>(pp);
        float4 v1 = *reinterpret_cast<const float4*>(pp + 4);
        *reinterpret_cast<bf16x8*>(&Ps[r][c8]) = cvt8(v0, v1);
    }
    {
        int j = tid >> 2, dg = tid & 3;
        const short* kr = kqvb + ((size_t)(b * TT + j0 + j)) * N_KQV + h * DD + dg * 16;
        const short* qr = kr + 256;
        float s = 0.f;
#pragma unroll
        for (int c = 0; c < 16; c += 8) {
            bf16x8 kv = *reinterpret_cast<const bf16x8*>(kr + c);
            bf16x8 qv = *reinterpret_cast<const bf16x8*>(qr + c);
#pragma unroll
            for (int q = 0; q < 8; ++q) s += bf2f(kv[q]) * bf2f(qv[q]);
        }
        part[j][dg] = s;
    }
    __syncthreads();
    if (tid < 64) dq[tid] = part[tid][0] + part[tid][1] + part[tid][2] + part[tid][3];
    __syncthreads();

    const int wv = tid >> 6, lane = tid & 63;
    const int col = lane & 15, kg = lane >> 4;
    f32x4 acc[4];
#pragma unroll
    for (int n = 0; n < 4; ++n) acc[n] = (f32x4){0.f, 0.f, 0.f, 0.f};

#pragma unroll
    for (int ks = 0; ks < 2; ++ks) {
        bf16x8 af = *reinterpret_cast<const bf16x8*>(&Qs[wv * 16 + col][ks * 32 + kg * 8]);
#pragma unroll
        for (int n = 0; n < 4; ++n) {
            bf16x8 bfr = *reinterpret_cast<const bf16x8*>(&Ps[n * 16 + col][ks * 32 + kg * 8]);
            acc[n] = __builtin_amdgcn_mfma_f32_16x16x32_bf16(af, bfr, acc[n], 0, 0, 0);
        }
    }

#pragma unroll
    for (int n = 0; n < 4; ++n) {
#pragma unroll
        for (int r = 0; r < 4; ++r) {
            int jl = wv * 16 + kg * 4 + r;
            int j = j0 + jl;
            int w = n * 16 + col;
            int t = j + 63 - w;
            if (t < TQ)
                scores[(((size_t)(b * HH + h) * TQ + t) << 6) + w] =
                    (acc[n][r] + dq[jl]) * 0.125f;
        }
    }
}

// ---------------------------------------------------------------------------
// K3: fused softmax + PV (MFMA).  Block per (b,h,64-t tile), 4 waves x 16 rows.
// ---------------------------------------------------------------------------
#define OFF_VT 0                        // bf16 [64][168]  vT[d][j']
#define OFF_VP 10752                    // bf16 [64][72]   vpT[d][w]
#define OFF_PP 15360                    // per-wave bf16 [16][104] banded
#define OFF_PD (15360 + 4*1664)         // per-wave bf16 [16][72]  dense
#define LDS_U16 (15360 + 4*1664 + 4*1152)

__global__ __launch_bounds__(256)
void attn_fused(const short* __restrict__ kqvb, const float* __restrict__ scores,
                const float* __restrict__ v_pos, float* __restrict__ wei_out,
                short* __restrict__ attnSb) {
    __shared__ short lds[LDS_U16];

    const int tid  = threadIdx.x;
    const int wv   = tid >> 6;
    const int lane = tid & 63;
    const int bid  = blockIdx.x;
    const int tile = bid & 31;
    const int h    = (bid >> 5) & 3;
    const int b    = bid >> 7;
    const int t0   = tile * 64;

    // ---- stage vT (transposed): rows j' = 0..159, j = t0-63+j'
#pragma unroll
    for (int it = 0; it < 5; ++it) {
        int fi = tid + it * 256;        // 0..1279
        int r = fi >> 3, c8 = (fi & 7) << 3;
        int j = t0 - 63 + r;
        bf16x8 v = (bf16x8){0, 0, 0, 0, 0, 0, 0, 0};
        if (j >= 0 && j < TT)
            v = *reinterpret_cast<const bf16x8*>(
                kqvb + ((size_t)(b * TT + j)) * N_KQV + 512 + h * DD + c8);
#pragma unroll
        for (int q = 0; q < 8; ++q) lds[OFF_VT + (c8 + q) * 168 + r] = v[q];
    }
    // ---- stage vpT
#pragma unroll
    for (int it = 0; it < 2; ++it) {
        int fi = tid + it * 256;
        int w = fi >> 3, c8 = (fi & 7) << 3;
        const float* pp = v_pos + (size_t)(w * HH + h) * DD + c8;
        float4 v0 = *reinterpret_cast<const float4*>(pp);
        float4 v1 = *reinterpret_cast<const float4*>(pp + 4);
        bf16x8 v = cvt8(v0, v1);
#pragma unroll
        for (int q = 0; q < 8; ++q) lds[OFF_VP + (c8 + q) * 72 + w] = v[q];
    }
    // ---- zero banded P'
    {
        unsigned int* pz = reinterpret_cast<unsigned int*>(lds + OFF_PP);
#pragma unroll
        for (int i = 0; i < 13; ++i) pz[tid + i * 256] = 0u;
    }
    __syncthreads();

    // ---- softmax; wave wv owns t = ta..ta+15
    const int ta = t0 + wv * 16;
    const int w  = lane;
#pragma unroll
    for (int i = 0; i < 16; ++i) {
        int t = ta + i;
        float wei = 0.f;
        if (t < TQ) {
            int j = t - 63 + w;
            float s = (j >= 0)
                ? scores[(((size_t)(b * HH + h) * TQ + t) << 6) + w]
                : -INFINITY;
            float m = s;
#pragma unroll
            for (int off = 32; off; off >>= 1) m = fmaxf(m, __shfl_xor(m, off));
            float p = (j >= 0) ? __expf(s - m) : 0.f;
            float sum = p;
#pragma unroll
            for (int off = 32; off; off >>= 1) sum += __shfl_xor(sum, off);
            wei = p / sum;
            wei_out[(((size_t)b * TQ + t) * WW + w) * HH + h] = wei;
        }
        short wb = f2bf(wei);
        lds[OFF_PD + wv * 1152 + i * 72 + w]        = wb;
        lds[OFF_PP + wv * 1664 + i * 104 + (i + w)] = wb;
    }

    // ---- MFMA PV
    const int col = lane & 15;
    const int kg  = lane >> 4;
    f32x4 acc[4];
#pragma unroll
    for (int dt = 0; dt < 4; ++dt) acc[dt] = (f32x4){0.f, 0.f, 0.f, 0.f};

    const int jbase = wv * 16;
#pragma unroll
    for (int ks = 0; ks < 3; ++ks) {
        bf16x8 afrag = *reinterpret_cast<const bf16x8*>(
            &lds[OFF_PP + wv * 1664 + col * 104 + ks * 32 + kg * 8]);
#pragma unroll
        for (int dt = 0; dt < 4; ++dt) {
            bf16x8 bfrag = *reinterpret_cast<const bf16x8*>(
                &lds[OFF_VT + (dt * 16 + col) * 168 + jbase + ks * 32 + kg * 8]);
            acc[dt] = __builtin_amdgcn_mfma_f32_16x16x32_bf16(afrag, bfrag, acc[dt], 0, 0, 0);
        }
    }
#pragma unroll
    for (int ks = 0; ks < 2; ++ks) {
        bf16x8 afrag = *reinterpret_cast<const bf16x8*>(
            &lds[OFF_PD + wv * 1152 + col * 72 + ks * 32 + kg * 8]);
#pragma unroll
        for (int dt = 0; dt < 4; ++dt) {
            bf16x8 bfrag = *reinterpret_cast<const bf16x8*>(
                &lds[OFF_VP + (dt * 16 + col) * 72 + ks * 32 + kg * 8]);
            acc[dt] = __builtin_amdgcn_mfma_f32_16x16x32_bf16(afrag, bfrag, acc[dt], 0, 0, 0);
        }
    }

    // ---- write attnS (bf16) shifted by +1 row
#pragma unroll
    for (int dt = 0; dt < 4; ++dt) {
#pragma unroll
        for (int r = 0; r < 4; ++r) {
            int t = ta + kg * 4 + r;
            if (t < TQ)
                attnSb[((size_t)(b * TT) + t + 1) * CC + h * DD + dt * 16 + col] =
                    f2bf(acc[dt][r]);
        }
    }
}

// ---------------------------------------------------------------------------
extern "C" void kernel_launch(void* const* d_in, const int* in_sizes, int n_in,
                              void* d_out, int out_size, void* d_ws, size_t ws_size,
                              hipStream_t stream) {
    const float* x     = (const float*)d_in[0];
    const float* w_kqv = (const float*)d_in[1];
    const float* w_out = (const float*)d_in[2];
    const float* b_out = (const float*)d_in[3];
    const float* q_pos = (const float*)d_in[4];
    const float* v_pos = (const float*)d_in[5];

    float* y   = (float*)d_out;
    float* wei = (float*)d_out + (size_t)BB * TT * CC;

    short* kqvb   = (short*)d_ws;                          // bf16 (B*T, 768)
    short* attnSb = kqvb + (size_t)BB * TT * N_KQV;        // bf16 (B*T, 256)
    float* scores = (float*)(attnSb + (size_t)BB * TT * CC);

    // K1: kqv = x @ w_kqv^T  (bf16 MFMA, bf16 out)
    gemm_mfma<false, 128, 128, 2, 2, false, false, true>
        <<<dim3((BB * TT) / 128, N_KQV / 128), 256, 0, stream>>>(
            x, w_kqv, nullptr, kqvb, BB * TT, N_KQV, CC);

    // K2: pre-shifted scaled scores
    score_gemm<<<BB * HH * 32, 256, 0, stream>>>(kqvb, q_pos, scores);

    // K3: softmax + MFMA PV
    attn_fused<<<BB * HH * 32, 256, 0, stream>>>(kqvb, scores, v_pos, wei, attnSb);

    // K4: y = attnS @ w_out^T + b_out  (bf16 MFMA, f32 out, t==0 rows zero)
    gemm_mfma<true, 64, 64, 2, 2, true, true, false>
        <<<dim3((BB * TT) / 64, CC / 64), 256, 0, stream>>>(
            attnSb, w_out, b_out, y, BB * TT, CC, CC);
}

// Round 4
// 34.877 us; speedup vs baseline: 5.5743x; 1.4073x over previous
//
#include <hip/hip_runtime.h>
#include <hip/hip_bf16.h>
#include <math.h>

#define BB 2
#define TT 2048
#define CC 256
#define HH 4
#define DD 64
#define WW 64
#define TQ 2047
#define N_KQV 768

typedef __attribute__((ext_vector_type(8))) short bf16x8;
typedef __attribute__((ext_vector_type(4))) float f32x4;

__device__ inline short f2bf(float x) {
    unsigned u = __float_as_uint(x);
    u += 0x7FFF + ((u >> 16) & 1);
    return (short)(u >> 16);
}
__device__ inline float bf2f(short s) {
    return __uint_as_float(((unsigned)(unsigned short)s) << 16);
}
__device__ inline bf16x8 cvt8(float4 a, float4 b) {
    bf16x8 r;
    r[0] = f2bf(a.x); r[1] = f2bf(a.y); r[2] = f2bf(a.z); r[3] = f2bf(a.w);
    r[4] = f2bf(b.x); r[5] = f2bf(b.y); r[6] = f2bf(b.z); r[7] = f2bf(b.w);
    return r;
}

// ---------------------------------------------------------------------------
// bf16-MFMA GEMM: C[M,N] = A[M,K] @ B[N,K]^T (+bias).  BK=64.
// A: f32 (converted in staging) or bf16 per ABF.  B: f32 weights.
// C: bf16 or f32 per CBF.  ZROW: rows with (m % 2048)==0 read as zero.
// ---------------------------------------------------------------------------
template<bool ABF, int BM, int BN, int WR, int WC, bool ZROW, bool BIAS, bool CBF>
__global__ __launch_bounds__(256)
void gemm_mfma(const void* __restrict__ Av, const float* __restrict__ Bm,
               const float* __restrict__ bias, void* __restrict__ Cv,
               int M, int N, int K) {
    constexpr int BK = 64;
    constexpr int LDA = BK + 8;
    constexpr int MR = BM / (WR * 16);
    constexpr int NR = BN / (WC * 16);
    __shared__ short As[BM][LDA];
    __shared__ short Bs[BN][LDA];

    const int tid = threadIdx.x;
    const int m0 = blockIdx.x * BM, n0 = blockIdx.y * BN;
    const int wv = tid >> 6, lane = tid & 63;
    const int wr = wv / WC, wc = wv % WC;
    const int col = lane & 15, kg = lane >> 4;

    f32x4 acc[MR][NR];
#pragma unroll
    for (int i = 0; i < MR; ++i)
#pragma unroll
        for (int j = 0; j < NR; ++j) acc[i][j] = (f32x4){0.f, 0.f, 0.f, 0.f};

    for (int k0 = 0; k0 < K; k0 += BK) {
#pragma unroll
        for (int it = 0; it < BM / 32; ++it) {
            int fi = tid + it * 256;
            int r = fi >> 3, c8 = (fi & 7) << 3;
            int gr = m0 + r;
            bf16x8 sv;
            if (ZROW && ((gr & (TT - 1)) == 0)) {
                sv = (bf16x8){0, 0, 0, 0, 0, 0, 0, 0};
            } else if constexpr (ABF) {
                sv = *reinterpret_cast<const bf16x8*>(
                    (const short*)Av + (size_t)gr * K + k0 + c8);
            } else {
                const float* ap = (const float*)Av + (size_t)gr * K + k0 + c8;
                float4 v0 = *reinterpret_cast<const float4*>(ap);
                float4 v1 = *reinterpret_cast<const float4*>(ap + 4);
                sv = cvt8(v0, v1);
            }
            *reinterpret_cast<bf16x8*>(&As[r][c8]) = sv;
        }
#pragma unroll
        for (int it = 0; it < BN / 32; ++it) {
            int fi = tid + it * 256;
            int r = fi >> 3, c8 = (fi & 7) << 3;
            const float* bp = Bm + (size_t)(n0 + r) * K + k0 + c8;
            float4 v0 = *reinterpret_cast<const float4*>(bp);
            float4 v1 = *reinterpret_cast<const float4*>(bp + 4);
            *reinterpret_cast<bf16x8*>(&Bs[r][c8]) = cvt8(v0, v1);
        }
        __syncthreads();

#pragma unroll
        for (int kk = 0; kk < 2; ++kk) {
            bf16x8 af[MR], bfr[NR];
#pragma unroll
            for (int i = 0; i < MR; ++i)
                af[i] = *reinterpret_cast<const bf16x8*>(
                    &As[wr * MR * 16 + i * 16 + col][kk * 32 + kg * 8]);
#pragma unroll
            for (int j = 0; j < NR; ++j)
                bfr[j] = *reinterpret_cast<const bf16x8*>(
                    &Bs[wc * NR * 16 + j * 16 + col][kk * 32 + kg * 8]);
#pragma unroll
            for (int i = 0; i < MR; ++i)
#pragma unroll
                for (int j = 0; j < NR; ++j)
                    acc[i][j] = __builtin_amdgcn_mfma_f32_16x16x32_bf16(
                        af[i], bfr[j], acc[i][j], 0, 0, 0);
        }
        __syncthreads();
    }

#pragma unroll
    for (int i = 0; i < MR; ++i) {
#pragma unroll
        for (int j = 0; j < NR; ++j) {
#pragma unroll
            for (int r = 0; r < 4; ++r) {
                int m = m0 + wr * MR * 16 + i * 16 + kg * 4 + r;
                int n = n0 + wc * NR * 16 + j * 16 + col;
                float v = acc[i][j][r];
                if (BIAS) v += bias[n];
                if constexpr (CBF)
                    ((short*)Cv)[(size_t)m * N + n] = f2bf(v);
                else
                    ((float*)Cv)[(size_t)m * N + n] = v;
            }
        }
    }
}

// ---------------------------------------------------------------------------
// Fused attention: scores (qq MFMA + dq) -> banded LDS -> softmax -> PV MFMA.
// One block per (b, h, 64-t tile), 4 waves.  j0 = t0-63 (halo of 128 q rows).
// LDS layout (shorts), regions aliased across phases:
//   [0..11264)    phase1-2: QS [128][72];  phase3+: PP 4x[16][104] + PD 4x[16][72]
//   [11264..15872) PS  [64][72]   q_pos bf16
//   [15872..26624) VT  [64][168]  v transposed bf16 (160 j-rows)
//   [26624..31232) VP  [64][72]   v_pos transposed bf16
//   [31232..39936) phase1-2: PT f32 [128][9]; phase3+: SB f32 [64][68]
//   [39936..40192) DQ f32 [128]
// ---------------------------------------------------------------------------
__global__ __launch_bounds__(256)
void attn_fused(const short* __restrict__ kqvb, const float* __restrict__ q_pos,
                const float* __restrict__ v_pos, float* __restrict__ wei_out,
                short* __restrict__ attnSb) {
    __shared__ __align__(16) short lds[40192];
    float* ldsf = reinterpret_cast<float*>(lds);
    short* QS = lds;                 // [128][72]
    short* PP = lds;                 // 4 x [16][104]
    short* PD = lds + 6656;          // 4 x [16][72]
    short* PS = lds + 11264;         // [64][72]
    short* VT = lds + 15872;         // [64][168]
    short* VP = lds + 26624;         // [64][72]
    float* PT = ldsf + 15616;        // [128][9]
    float* SB = ldsf + 15616;        // [64][68]
    float* DQ = ldsf + 19968;        // [128]

    const int tid  = threadIdx.x;
    const int wv   = tid >> 6;
    const int lane = tid & 63;
    const int col  = lane & 15;
    const int kg   = lane >> 4;
    const int bid  = blockIdx.x;
    const int tile = bid & 31;
    const int h    = (bid >> 5) & 3;
    const int b    = bid >> 7;
    const int t0   = tile * 64;
    const int j0   = t0 - 63;

    // ================= phase 1: stage =================
#pragma unroll
    for (int it = 0; it < 4; ++it) {          // QS rows 0..127 + k.q partials
        int fi = tid + it * 256;
        int r = fi >> 3, c8 = (fi & 7) << 3;
        int j = j0 + r;
        bf16x8 qv = (bf16x8){0,0,0,0,0,0,0,0};
        bf16x8 kv = (bf16x8){0,0,0,0,0,0,0,0};
        if (j >= 0 && j < TT) {
            const short* base = kqvb + ((size_t)(b * TT + j)) * N_KQV + h * DD + c8;
            kv = *reinterpret_cast<const bf16x8*>(base);
            qv = *reinterpret_cast<const bf16x8*>(base + 256);
        }
        *reinterpret_cast<bf16x8*>(&QS[r * 72 + c8]) = qv;
        float s = 0.f;
#pragma unroll
        for (int q = 0; q < 8; ++q) s += bf2f(kv[q]) * bf2f(qv[q]);
        PT[r * 9 + (fi & 7)] = s;
    }
#pragma unroll
    for (int it = 0; it < 2; ++it) {          // PS (q_pos)
        int fi = tid + it * 256;
        int r = fi >> 3, c8 = (fi & 7) << 3;
        const float* pp = q_pos + (size_t)(r * HH + h) * DD + c8;
        float4 v0 = *reinterpret_cast<const float4*>(pp);
        float4 v1 = *reinterpret_cast<const float4*>(pp + 4);
        *reinterpret_cast<bf16x8*>(&PS[r * 72 + c8]) = cvt8(v0, v1);
    }
#pragma unroll
    for (int it = 0; it < 5; ++it) {          // VT rows 0..159 (transposed)
        int fi = tid + it * 256;
        int r = fi >> 3, c8 = (fi & 7) << 3;
        int j = j0 + r;
        bf16x8 v = (bf16x8){0,0,0,0,0,0,0,0};
        if (j >= 0 && j < TT)
            v = *reinterpret_cast<const bf16x8*>(
                kqvb + ((size_t)(b * TT + j)) * N_KQV + 512 + h * DD + c8);
#pragma unroll
        for (int q = 0; q < 8; ++q) VT[(c8 + q) * 168 + r] = v[q];
    }
#pragma unroll
    for (int it = 0; it < 2; ++it) {          // VP (v_pos transposed)
        int fi = tid + it * 256;
        int r = fi >> 3, c8 = (fi & 7) << 3;
        const float* pp = v_pos + (size_t)(r * HH + h) * DD + c8;
        float4 v0 = *reinterpret_cast<const float4*>(pp);
        float4 v1 = *reinterpret_cast<const float4*>(pp + 4);
        bf16x8 v = cvt8(v0, v1);
#pragma unroll
        for (int q = 0; q < 8; ++q) VP[(c8 + q) * 72 + r] = v[q];
    }
    __syncthreads();

    // ================= phase 2: qq MFMA + dq reduce =================
    f32x4 qacc[2][4];
#pragma unroll
    for (int mi = 0; mi < 2; ++mi)
#pragma unroll
        for (int n = 0; n < 4; ++n) qacc[mi][n] = (f32x4){0.f, 0.f, 0.f, 0.f};

#pragma unroll
    for (int ks = 0; ks < 2; ++ks) {
        bf16x8 af[2], bfr[4];
#pragma unroll
        for (int mi = 0; mi < 2; ++mi)
            af[mi] = *reinterpret_cast<const bf16x8*>(
                &QS[(wv * 32 + mi * 16 + col) * 72 + ks * 32 + kg * 8]);
#pragma unroll
        for (int n = 0; n < 4; ++n)
            bfr[n] = *reinterpret_cast<const bf16x8*>(
                &PS[(n * 16 + col) * 72 + ks * 32 + kg * 8]);
#pragma unroll
        for (int mi = 0; mi < 2; ++mi)
#pragma unroll
            for (int n = 0; n < 4; ++n)
                qacc[mi][n] = __builtin_amdgcn_mfma_f32_16x16x32_bf16(
                    af[mi], bfr[n], qacc[mi][n], 0, 0, 0);
    }
    if (tid < 128) {
        float s = 0.f;
#pragma unroll
        for (int g = 0; g < 8; ++g) s += PT[tid * 9 + g];
        DQ[tid] = s;
    }
    __syncthreads();   // QS/PT dead after this point

    // ================= phase 3: zero PP/PD, scatter SB =================
    {
        unsigned int* pz = reinterpret_cast<unsigned int*>(lds);
#pragma unroll
        for (int i = 0; i < 22; ++i) pz[tid + i * 256] = 0u;   // 5632 u32
    }
#pragma unroll
    for (int mi = 0; mi < 2; ++mi) {
#pragma unroll
        for (int n = 0; n < 4; ++n) {
            int w = n * 16 + col;
#pragma unroll
            for (int r = 0; r < 4; ++r) {
                int jl = wv * 32 + mi * 16 + kg * 4 + r;
                int it_ = jl - w;
                if (it_ >= 0 && it_ < 64) SB[it_ * 68 + w] = qacc[mi][n][r];
            }
        }
    }
    __syncthreads();

    // ================= phase 4: softmax (4 rows in parallel) =================
    const int rs = lane >> 4;      // row-in-group
    const int wg = lane & 15;      // w quad
    const bool edge = (t0 == 0);
#pragma unroll
    for (int i4 = 0; i4 < 4; ++i4) {
        int i = wv * 16 + i4 * 4 + rs;          // row in [0,64)
        int t = t0 + i;
        f32x4 sv = *reinterpret_cast<const f32x4*>(&SB[i * 68 + wg * 4]);
        float s[4];
#pragma unroll
        for (int q = 0; q < 4; ++q) {
            int w = wg * 4 + q;
            s[q] = (sv[q] + DQ[i + w]) * 0.125f;
            if (edge && (i - 63 + w) < 0) s[q] = -INFINITY;
        }
        float m = fmaxf(fmaxf(s[0], s[1]), fmaxf(s[2], s[3]));
#pragma unroll
        for (int off = 8; off; off >>= 1) m = fmaxf(m, __shfl_xor(m, off));
        float p[4], sum = 0.f;
#pragma unroll
        for (int q = 0; q < 4; ++q) { p[q] = __expf(s[q] - m); sum += p[q]; }
#pragma unroll
        for (int off = 8; off; off >>= 1) sum += __shfl_xor(sum, off);
        float inv = 1.f / sum;
        int il = i4 * 4 + rs;                   // row within wave's 16
#pragma unroll
        for (int q = 0; q < 4; ++q) {
            int w = wg * 4 + q;
            float wei = p[q] * inv;
            if (t < TQ)
                wei_out[(((size_t)b * TQ + t) * WW + w) * HH + h] = wei;
            short wb = f2bf(wei);
            PD[wv * 1152 + il * 72 + w] = wb;
            PP[wv * 1664 + il * 104 + il + w] = wb;
        }
    }
    __syncthreads();

    // ================= phase 5: PV MFMA =================
    f32x4 pacc[4];
#pragma unroll
    for (int dt = 0; dt < 4; ++dt) pacc[dt] = (f32x4){0.f, 0.f, 0.f, 0.f};
    const int jbase = wv * 16;
#pragma unroll
    for (int ks = 0; ks < 3; ++ks) {
        bf16x8 afrag = *reinterpret_cast<const bf16x8*>(
            &PP[wv * 1664 + col * 104 + ks * 32 + kg * 8]);
#pragma unroll
        for (int dt = 0; dt < 4; ++dt) {
            bf16x8 bfrag = *reinterpret_cast<const bf16x8*>(
                &VT[(dt * 16 + col) * 168 + jbase + ks * 32 + kg * 8]);
            pacc[dt] = __builtin_amdgcn_mfma_f32_16x16x32_bf16(afrag, bfrag, pacc[dt], 0, 0, 0);
        }
    }
#pragma unroll
    for (int ks = 0; ks < 2; ++ks) {
        bf16x8 afrag = *reinterpret_cast<const bf16x8*>(
            &PD[wv * 1152 + col * 72 + ks * 32 + kg * 8]);
#pragma unroll
        for (int dt = 0; dt < 4; ++dt) {
            bf16x8 bfrag = *reinterpret_cast<const bf16x8*>(
                &VP[(dt * 16 + col) * 72 + ks * 32 + kg * 8]);
            pacc[dt] = __builtin_amdgcn_mfma_f32_16x16x32_bf16(afrag, bfrag, pacc[dt], 0, 0, 0);
        }
    }

    const int ta = t0 + wv * 16;
#pragma unroll
    for (int dt = 0; dt < 4; ++dt) {
#pragma unroll
        for (int r = 0; r < 4; ++r) {
            int t = ta + kg * 4 + r;
            if (t < TQ)
                attnSb[((size_t)(b * TT) + t + 1) * CC + h * DD + dt * 16 + col] =
                    f2bf(pacc[dt][r]);
        }
    }
}

// ---------------------------------------------------------------------------
extern "C" void kernel_launch(void* const* d_in, const int* in_sizes, int n_in,
                              void* d_out, int out_size, void* d_ws, size_t ws_size,
                              hipStream_t stream) {
    const float* x     = (const float*)d_in[0];
    const float* w_kqv = (const float*)d_in[1];
    const float* w_out = (const float*)d_in[2];
    const float* b_out = (const float*)d_in[3];
    const float* q_pos = (const float*)d_in[4];
    const float* v_pos = (const float*)d_in[5];

    float* y   = (float*)d_out;
    float* wei = (float*)d_out + (size_t)BB * TT * CC;

    short* kqvb   = (short*)d_ws;                          // bf16 (B*T, 768)
    short* attnSb = kqvb + (size_t)BB * TT * N_KQV;        // bf16 (B*T, 256)

    // K1: kqv = x @ w_kqv^T  (bf16 MFMA, bf16 out), 64x96 tiles -> 512 blocks
    gemm_mfma<false, 64, 96, 2, 2, false, false, true>
        <<<dim3((BB * TT) / 64, N_KQV / 96), 256, 0, stream>>>(
            x, w_kqv, nullptr, kqvb, BB * TT, N_KQV, CC);

    // K2: fused scores + softmax + PV
    attn_fused<<<BB * HH * 32, 256, 0, stream>>>(kqvb, q_pos, v_pos, wei, attnSb);

    // K3: y = attnS @ w_out^T + b_out  (32x64 tiles -> 512 blocks)
    gemm_mfma<true, 32, 64, 2, 2, true, true, false>
        <<<dim3((BB * TT) / 32, CC / 64), 256, 0, stream>>>(
            attnSb, w_out, b_out, y, BB * TT, CC, CC);
}